// Round 14
// baseline (360.077 us; speedup 1.0000x reference)
//
#include <hip/hip_runtime.h>
#include <hip/hip_bf16.h>
#include <hip/hip_fp16.h>

#define EPS 1e-5f
#define HB 128         // histogram/fill blocks (EperB = 6250 < 2^16)
#define HRANGE 25600   // packed u16-pair counters: covers 51200 nodes in 100KB
#define NN2 51200      // 2*HRANGE >= N

typedef __attribute__((ext_vector_type(8))) short short8;
typedef __attribute__((ext_vector_type(4))) float f32x4;

__device__ __forceinline__ unsigned short f2bf_rn(float f) {
    unsigned u = __builtin_bit_cast(unsigned, f);
    u += 0x7fffu + ((u >> 16) & 1u);
    return (unsigned short)(u >> 16);
}
__device__ __forceinline__ float bf2f(unsigned short h) {
    return __builtin_bit_cast(float, (unsigned)h << 16);
}
// pack fp32 -> (bf16 hi | bf16 lo) in one u32
__device__ __forceinline__ unsigned packsplit(float x) {
    unsigned short h = f2bf_rn(x);
    unsigned short l = f2bf_rn(x - bf2f(h));
    return ((unsigned)h << 16) | l;
}

// ---------------------------------------------------------------------------
// K1: per-block LDS histograms (u16-packed pairs, full node range).
// 2*HB blocks: blocks [0,HB) histogram dst, [HB,2HB) histogram src — one
// edge pass per block, all CUs busy. No global atomics.
__global__ __launch_bounds__(1024) void hist_kernel(
    const int* __restrict__ src, const int* __restrict__ dst,
    unsigned* __restrict__ histW, int E, int EperB) {
    __shared__ unsigned cnt[HRANGE];
    const int bb = blockIdx.x;
    const int arr = (bb >= HB) ? 1 : 0;
    const int b = arr ? (bb - HB) : bb;
    const int tid = threadIdx.x;
    const int* a = arr ? src : dst;
    const long e0 = (long)b * EperB;
    const long e1 = min(e0 + (long)EperB, (long)E);
    for (int j = tid; j < HRANGE; j += 1024) cnt[j] = 0;
    __syncthreads();
    for (long e = e0 + tid; e < e1; e += 1024) {
        int v = a[e];
        atomicAdd(&cnt[v >> 1], 1u << ((v & 1) << 4));
    }
    __syncthreads();
    unsigned* o = histW + ((size_t)(arr * HB + b)) * HRANGE;
    for (int j = tid; j < HRANGE; j += 1024) o[j] = cnt[j];
}

// K2: merge per-block hists -> padded degree (multiple of 8), norms, bp16 prefix
__global__ __launch_bounds__(256) void merge_kernel(
    const unsigned short* __restrict__ hist16, int* __restrict__ pdeg,
    unsigned short* __restrict__ bp16, float* __restrict__ nsrc,
    float* __restrict__ ndst, int N) {
    int n = blockIdx.x * blockDim.x + threadIdx.x;
    if (n >= NN2) return;
    unsigned s = 0;
    #pragma unroll 8
    for (int b = 0; b < HB; ++b) {
        unsigned c = hist16[(size_t)b * NN2 + n];
        bp16[(size_t)b * NN2 + n] = (unsigned short)s;
        s += c;
    }
    unsigned s2 = 0;
    #pragma unroll 8
    for (int b = 0; b < HB; ++b) s2 += hist16[(size_t)(HB + b) * NN2 + n];
    if (n < N) {
        pdeg[n] = (int)((s + 7u) & ~7u);   // pad to multiple of 8 (pads -> zero row)
        ndst[n] = rsqrtf((float)max((int)s, 1));
        nsrc[n] = rsqrtf((float)max((int)s2, 1));
    }
}

// ---------------------------------------------------------------------------
// Multi-block exclusive scan of padded degrees -> CSC offsets (all 8-aligned)
__global__ __launch_bounds__(256) void scan_partial_kernel(const int* __restrict__ deg,
                                                           int* __restrict__ bsums, int n) {
    __shared__ int wsum[4];
    const int tid = threadIdx.x, lane = tid & 63, wid = tid >> 6;
    const int i0 = blockIdx.x * 1024 + tid * 4;
    int s = 0;
    if (i0 + 3 < n) {
        int4 v = *(const int4*)(deg + i0);
        s = v.x + v.y + v.z + v.w;
    } else {
        for (int j = 0; j < 4; ++j) if (i0 + j < n) s += deg[i0 + j];
    }
    #pragma unroll
    for (int off = 32; off >= 1; off >>= 1) s += __shfl_down(s, off, 64);
    if (lane == 0) wsum[wid] = s;
    __syncthreads();
    if (tid == 0) bsums[blockIdx.x] = wsum[0] + wsum[1] + wsum[2] + wsum[3];
}

__global__ __launch_bounds__(64) void scan_bsums_kernel(int* __restrict__ bsums,
                                                        int* __restrict__ offs, int nb, int n) {
    int lane = threadIdx.x;
    int v = (lane < nb) ? bsums[lane] : 0;
    int x = v;
    #pragma unroll
    for (int off = 1; off < 64; off <<= 1) {
        int t = __shfl_up(x, off, 64);
        if (lane >= off) x += t;
    }
    if (lane < nb) bsums[lane] = x - v;
    if (lane == 63) offs[n] = x;
}

__global__ __launch_bounds__(256) void scan_final_kernel(const int* __restrict__ deg,
                                                         const int* __restrict__ bsums,
                                                         int* __restrict__ offs, int n) {
    __shared__ int wsum[4];
    const int tid = threadIdx.x, lane = tid & 63, wid = tid >> 6;
    const int i0 = blockIdx.x * 1024 + tid * 4;
    int d0 = 0, d1 = 0, d2 = 0, d3 = 0;
    if (i0 + 3 < n) {
        int4 v = *(const int4*)(deg + i0);
        d0 = v.x; d1 = v.y; d2 = v.z; d3 = v.w;
    } else {
        if (i0 + 0 < n) d0 = deg[i0 + 0];
        if (i0 + 1 < n) d1 = deg[i0 + 1];
        if (i0 + 2 < n) d2 = deg[i0 + 2];
        if (i0 + 3 < n) d3 = deg[i0 + 3];
    }
    int s = d0 + d1 + d2 + d3;
    int x = s;
    #pragma unroll
    for (int off = 1; off < 64; off <<= 1) {
        int t = __shfl_up(x, off, 64);
        if (lane >= off) x += t;
    }
    if (lane == 63) wsum[wid] = x;
    __syncthreads();
    int wpre = 0;
    #pragma unroll
    for (int w = 0; w < 4; ++w) if (w < wid) wpre += wsum[w];
    int base = bsums[blockIdx.x] + wpre + (x - s);
    if (i0 + 0 < n) offs[i0 + 0] = base;
    if (i0 + 1 < n) offs[i0 + 1] = base + d0;
    if (i0 + 2 < n) offs[i0 + 2] = base + d0 + d1;
    if (i0 + 3 < n) offs[i0 + 3] = base + d0 + d1 + d2;
}

// K3d: pre-fill csc pad slots with node index N (the zero row)
__global__ void fill_pad_kernel(int* __restrict__ csc, int total, int N) {
    int i = blockIdx.x * blockDim.x + threadIdx.x;
    int o = i * 4;
    if (o + 3 < total) {
        *(int4*)(csc + o) = make_int4(N, N, N, N);
    } else {
        for (int j = 0; j < 4 && o + j < total; ++j) csc[o + j] = N;
    }
}

// K4: single-pass CSC fill. LDS u16-packed local-rank cursors;
// csc position = offs[d] + bp16[b][d] + local_rank. No global atomics.
__global__ __launch_bounds__(1024) void fill_kernel(
    const int* __restrict__ src, const int* __restrict__ dst,
    const int* __restrict__ offs, const unsigned short* __restrict__ bp16,
    int* __restrict__ csc, int E, int EperB) {
    __shared__ unsigned cur[HRANGE];
    const int b = blockIdx.x, tid = threadIdx.x;
    const long e0 = (long)b * EperB;
    const long e1 = min(e0 + (long)EperB, (long)E);
    for (int j = tid; j < HRANGE; j += 1024) cur[j] = 0;
    __syncthreads();
    const unsigned short* bprow = bp16 + (size_t)b * NN2;
    for (long e = e0 + tid; e < e1; e += 1024) {
        int d = dst[e];
        int sh = (d & 1) << 4;
        unsigned old = atomicAdd(&cur[d >> 1], 1u << sh);
        unsigned rank = (old >> sh) & 0xffffu;
        unsigned p = (unsigned)offs[d] + (unsigned)bprow[d] + rank;
        csc[p] = src[e];
    }
}

// ---------------------------------------------------------------------------
// pack helper: one thread packs 8 elems of one MFMA fragment (cf-major order).
__device__ __forceinline__ void pack_frag(
    const float* __restrict__ B, short* __restrict__ hi, short* __restrict__ lo,
    int K, int NCF, int strideB, int ncols, int t) {
    int KF = K >> 5;
    int lane = t & 63;
    int fid = t >> 6;
    int cf = fid / KF;
    int kf = fid % KF;
    int col = cf * 16 + (lane & 15);
    int k0 = kf * 32 + (lane >> 4) * 8;
    int o = t * 8;
    #pragma unroll
    for (int j = 0; j < 8; ++j) {
        float x = (col < ncols) ? B[(size_t)(k0 + j) * strideB + col] : 0.f;
        unsigned short h = f2bf_rn(x);
        hi[o + j] = (short)h;
        lo[o + j] = (short)f2bf_rn(x - bf2f(h));
    }
}

// Kp: all weight packing in ONE launch.
__global__ __launch_bounds__(256) void pack_all_kernel(
    const float* __restrict__ enc_W, const float* __restrict__ cls_W0,
    const float* __restrict__ cls_W1,
    short* __restrict__ encBhi, short* __restrict__ encBlo,
    short* __restrict__ clsBhi, short* __restrict__ clsBlo,
    short* __restrict__ w1hi, short* __restrict__ w1lo) {
    int t = blockIdx.x * blockDim.x + threadIdx.x;
    if (t < 8192) {
        int i = t >> 11, tt = t & 2047;
        pack_frag(enc_W + (size_t)i * 128 * 128, encBhi + i * 16384, encBlo + i * 16384,
                  128, 8, 128, 128, tt);
    } else if (t < 16384) {
        pack_frag(cls_W0, clsBhi, clsBlo, 512, 8, 128, 128, t - 8192);
    } else if (t < 16384 + 768) {
        pack_frag(cls_W1, w1hi, w1lo, 128, 3, 47, 47, t - 16384);
    }
}

// ---------------------------------------------------------------------------
// K5: MFMA GEMM  C[M,128] (fp16) = norm_src_row * (A[M,128] @ B[128,128])
// B staged whole in LDS (64KB/block, shared by 4 waves). 32 rows/wave.
template<bool PACKED>
__global__ __launch_bounds__(256) void mfma_gemm_kernel(
    const void* __restrict__ Av, const short* __restrict__ Bhi, const short* __restrict__ Blo,
    const float* __restrict__ nsrc, __half* __restrict__ C, int M) {
    __shared__ short Bh_sh[16384];   // 32 KB
    __shared__ short Bl_sh[16384];   // 32 KB
    const int tid = threadIdx.x;
    const int lane = tid & 63;
    const int wid  = tid >> 6;
    const int row0 = blockIdx.x * 128 + wid * 32;
    const int rsub = lane & 15;
    const int kg   = lane >> 4;

    short8 ahi[2][4], alo[2][4];
    #pragma unroll
    for (int rf = 0; rf < 2; ++rf) {
        const int rowa = min(row0 + rf * 16 + rsub, M - 1);
        #pragma unroll
        for (int kf = 0; kf < 4; ++kf) {
            short8 h, l;
            if (PACKED) {
                const unsigned* ap = (const unsigned*)Av + (size_t)rowa * 128 + kg * 8;
                uint4 u0 = *(const uint4*)(ap + kf * 32);
                uint4 u1 = *(const uint4*)(ap + kf * 32 + 4);
                unsigned uu[8] = {u0.x, u0.y, u0.z, u0.w, u1.x, u1.y, u1.z, u1.w};
                #pragma unroll
                for (int j = 0; j < 8; ++j) {
                    h[j] = (short)(uu[j] >> 16);
                    l[j] = (short)(uu[j] & 0xffffu);
                }
            } else {
                const float* ap = (const float*)Av + (size_t)rowa * 128 + kg * 8;
                float4 v0 = *(const float4*)(ap + kf * 32);
                float4 v1 = *(const float4*)(ap + kf * 32 + 4);
                float v[8] = {v0.x, v0.y, v0.z, v0.w, v1.x, v1.y, v1.z, v1.w};
                #pragma unroll
                for (int j = 0; j < 8; ++j) {
                    unsigned short hb = f2bf_rn(v[j]);
                    h[j] = (short)hb;
                    l[j] = (short)f2bf_rn(v[j] - bf2f(hb));
                }
            }
            ahi[rf][kf] = h; alo[rf][kf] = l;
        }
    }

    #pragma unroll
    for (int i = 0; i < 8; ++i) {
        int o = (tid + i * 256) * 8;
        *(uint4*)&Bh_sh[o] = *(const uint4*)&Bhi[o];
        *(uint4*)&Bl_sh[o] = *(const uint4*)&Blo[o];
    }
    __syncthreads();

    f32x4 acc[2][8];
    #pragma unroll
    for (int rf = 0; rf < 2; ++rf)
        #pragma unroll
        for (int cf = 0; cf < 8; ++cf) acc[rf][cf] = (f32x4){0.f, 0.f, 0.f, 0.f};

    #pragma unroll
    for (int cf = 0; cf < 8; ++cf) {
        #pragma unroll
        for (int kf = 0; kf < 4; ++kf) {
            int o = ((cf * 4 + kf) * 64 + lane) * 8;
            short8 bh = *(const short8*)&Bh_sh[o];
            short8 bl = *(const short8*)&Bl_sh[o];
            #pragma unroll
            for (int rf = 0; rf < 2; ++rf) {
                acc[rf][cf] = __builtin_amdgcn_mfma_f32_16x16x32_bf16(ahi[rf][kf], bh, acc[rf][cf], 0, 0, 0);
                acc[rf][cf] = __builtin_amdgcn_mfma_f32_16x16x32_bf16(alo[rf][kf], bh, acc[rf][cf], 0, 0, 0);
                acc[rf][cf] = __builtin_amdgcn_mfma_f32_16x16x32_bf16(ahi[rf][kf], bl, acc[rf][cf], 0, 0, 0);
            }
        }
    }

    #pragma unroll
    for (int rf = 0; rf < 2; ++rf)
        #pragma unroll
        for (int r = 0; r < 4; ++r) {
            int row = row0 + rf * 16 + kg * 4 + r;
            if (row < M) {
                float sc = nsrc[row];
                __half* cp = C + (size_t)row * 128 + rsub;
                #pragma unroll
                for (int cf = 0; cf < 8; ++cf) cp[cf * 16] = __float2half(acc[rf][cf][r] * sc);
            }
        }
}

// ---------------------------------------------------------------------------
// K6: CSC aggregation. 2 nodes/wave: half-wave (32 lanes) covers one node,
// lane covers 4 cols (8B fp16 loads). 8-aligned padded segments (zero-row
// pads). 16 independent 8B gathers in flight per wave. + norm_dst + (bias)
// + BN + ReLU; writes packed (bf16hi|bf16lo) u32 (uint4/lane, coalesced).
__global__ __launch_bounds__(256) void aggregate_kernel(
    const __half* __restrict__ hw, const int* __restrict__ offs, const int* __restrict__ csc,
    const float* __restrict__ norm_dst, const float* __restrict__ bias,
    const float* __restrict__ gamma, const float* __restrict__ beta,
    const float* __restrict__ mean, const float* __restrict__ var,
    unsigned* __restrict__ hout, int n) {
    const int lane = threadIdx.x & 63;
    const int half = lane >> 5;
    const int c = (lane & 31) * 4;
    const int gw = (blockIdx.x * blockDim.x + threadIdx.x) >> 6;
    const int nw = (gridDim.x * blockDim.x) >> 6;

    float scv[4], mnv[4], btv[4], biv[4];
    #pragma unroll
    for (int j = 0; j < 4; ++j) {
        int col = c + j;
        scv[j] = gamma[col] * rsqrtf(var[col] + EPS);
        mnv[j] = mean[col];
        btv[j] = beta[col];
        biv[j] = bias ? bias[col] : 0.f;
    }

    for (int vb = gw * 2; vb < n; vb += nw * 2) {
        const int v = min(vb + half, n - 1);
        const int e0 = offs[v], e1 = offs[v + 1];   // multiples of 8
        float4 acc = make_float4(0.f, 0.f, 0.f, 0.f);
        for (int e = e0; e < e1; e += 8) {
            int4 ca = *(const int4*)(csc + e);
            int4 cb = *(const int4*)(csc + e + 4);
            uint2 u0 = *(const uint2*)(hw + (size_t)ca.x * 128 + c);
            uint2 u1 = *(const uint2*)(hw + (size_t)ca.y * 128 + c);
            uint2 u2 = *(const uint2*)(hw + (size_t)ca.z * 128 + c);
            uint2 u3 = *(const uint2*)(hw + (size_t)ca.w * 128 + c);
            uint2 u4 = *(const uint2*)(hw + (size_t)cb.x * 128 + c);
            uint2 u5 = *(const uint2*)(hw + (size_t)cb.y * 128 + c);
            uint2 u6 = *(const uint2*)(hw + (size_t)cb.z * 128 + c);
            uint2 u7 = *(const uint2*)(hw + (size_t)cb.w * 128 + c);
            uint2 uu[8] = {u0, u1, u2, u3, u4, u5, u6, u7};
            float4 a0 = make_float4(0.f, 0.f, 0.f, 0.f);
            float4 a1 = make_float4(0.f, 0.f, 0.f, 0.f);
            #pragma unroll
            for (int j = 0; j < 8; j += 2) {
                float2 fa = __half22float2(__builtin_bit_cast(__half2, uu[j].x));
                float2 fb = __half22float2(__builtin_bit_cast(__half2, uu[j].y));
                float2 ga = __half22float2(__builtin_bit_cast(__half2, uu[j + 1].x));
                float2 gb = __half22float2(__builtin_bit_cast(__half2, uu[j + 1].y));
                a0.x += fa.x; a0.y += fa.y; a0.z += fb.x; a0.w += fb.y;
                a1.x += ga.x; a1.y += ga.y; a1.z += gb.x; a1.w += gb.y;
            }
            acc.x += a0.x + a1.x;
            acc.y += a0.y + a1.y;
            acc.z += a0.z + a1.z;
            acc.w += a0.w + a1.w;
        }
        float nd = norm_dst[v];
        float av[4] = {acc.x, acc.y, acc.z, acc.w};
        uint4 w;
        unsigned wv[4];
        #pragma unroll
        for (int j = 0; j < 4; ++j) {
            float h = fmaxf((av[j] * nd + biv[j] - mnv[j]) * scv[j] + btv[j], 0.f);
            wv[j] = packsplit(h);
        }
        w = make_uint4(wv[0], wv[1], wv[2], wv[3]);
        if (vb + half < n)
            *(uint4*)(hout + (size_t)v * 128 + c) = w;
    }
}

// ---------------------------------------------------------------------------
// K7: fused classifier — R10 structure (empirically best: 40.6us).
// 32 rows/wave, 128-row blocks, dbuf 8KB-chunk staging (cf-major), 64KB LDS.
__global__ __launch_bounds__(256) void classifier_kernel(
    const unsigned* __restrict__ h1, const unsigned* __restrict__ h2,
    const unsigned* __restrict__ h3, const unsigned* __restrict__ h4,
    const short* __restrict__ Bhi, const short* __restrict__ Blo,
    const short* __restrict__ W1hi, const short* __restrict__ W1lo,
    const float* __restrict__ b0,
    const float* __restrict__ g, const float* __restrict__ bt,
    const float* __restrict__ mn, const float* __restrict__ vr,
    const float* __restrict__ b1,
    float* __restrict__ out, int M) {
    __shared__ short Bh_sh[2][4096];   // 2 x 8 KB
    __shared__ short Bl_sh[2][4096];   // 2 x 8 KB
    __shared__ unsigned zw[4][16 * 128];  // 32 KB, wave-private tiles
    const int tid = threadIdx.x, lane = tid & 63, wid = tid >> 6;
    const int rsub = lane & 15;
    const int kg   = lane >> 4;
    const int row0 = blockIdx.x * 128 + wid * 32;
    const unsigned* hb[4] = {h1, h2, h3, h4};

    const int scf = tid >> 5, ssub = tid & 31;
    const int sl = scf * 512 + ssub * 16;

    float biasv[8], scalev[8], meanv[8], betav[8];
    #pragma unroll
    for (int cf = 0; cf < 8; ++cf) {
        int col = cf * 16 + rsub;
        biasv[cf] = b0[col];
        scalev[cf] = g[col] * rsqrtf(vr[col] + EPS);
        meanv[cf] = mn[col];
        betav[cf] = bt[col];
    }

    f32x4 acc[2][8];
    #pragma unroll
    for (int rf = 0; rf < 2; ++rf)
        #pragma unroll
        for (int cf = 0; cf < 8; ++cf) acc[rf][cf] = (f32x4){0.f, 0.f, 0.f, 0.f};

    {   // prologue: stage chunk 0
        size_t goff = ((size_t)(scf * 16 + 0) * 64) * 8 + ssub * 16;
        *(uint4*)&Bh_sh[0][sl]     = *(const uint4*)&Bhi[goff];
        *(uint4*)&Bh_sh[0][sl + 8] = *(const uint4*)&Bhi[goff + 8];
        *(uint4*)&Bl_sh[0][sl]     = *(const uint4*)&Blo[goff];
        *(uint4*)&Bl_sh[0][sl + 8] = *(const uint4*)&Blo[goff + 8];
    }
    __syncthreads();

    const int rowa0 = min(row0 + rsub, M - 1);
    const int rowa1 = min(row0 + 16 + rsub, M - 1);

    for (int kf16 = 0; kf16 < 16; ++kf16) {
        const int cur = kf16 & 1;
        uint4 st0, st1, st2, st3;
        if (kf16 < 15) {
            size_t goff = ((size_t)(scf * 16 + kf16 + 1) * 64) * 8 + ssub * 16;
            st0 = *(const uint4*)&Bhi[goff];
            st1 = *(const uint4*)&Bhi[goff + 8];
            st2 = *(const uint4*)&Blo[goff];
            st3 = *(const uint4*)&Blo[goff + 8];
        }
        short8 ah[2], al[2];
        #pragma unroll
        for (int rf = 0; rf < 2; ++rf) {
            const unsigned* ap = hb[kf16 >> 2] + (size_t)(rf ? rowa1 : rowa0) * 128
                                 + (kf16 & 3) * 32 + kg * 8;
            uint4 u0 = *(const uint4*)(ap);
            uint4 u1 = *(const uint4*)(ap + 4);
            unsigned uu[8] = {u0.x, u0.y, u0.z, u0.w, u1.x, u1.y, u1.z, u1.w};
            #pragma unroll
            for (int j = 0; j < 8; ++j) {
                ah[rf][j] = (short)(uu[j] >> 16);
                al[rf][j] = (short)(uu[j] & 0xffffu);
            }
        }
        #pragma unroll
        for (int cf = 0; cf < 8; ++cf) {
            int o = (cf * 64 + lane) * 8;
            short8 bh = *(const short8*)&Bh_sh[cur][o];
            short8 bl = *(const short8*)&Bl_sh[cur][o];
            #pragma unroll
            for (int rf = 0; rf < 2; ++rf) {
                acc[rf][cf] = __builtin_amdgcn_mfma_f32_16x16x32_bf16(ah[rf], bh, acc[rf][cf], 0, 0, 0);
                acc[rf][cf] = __builtin_amdgcn_mfma_f32_16x16x32_bf16(al[rf], bh, acc[rf][cf], 0, 0, 0);
                acc[rf][cf] = __builtin_amdgcn_mfma_f32_16x16x32_bf16(ah[rf], bl, acc[rf][cf], 0, 0, 0);
            }
        }
        if (kf16 < 15) {
            *(uint4*)&Bh_sh[cur ^ 1][sl]     = st0;
            *(uint4*)&Bh_sh[cur ^ 1][sl + 8] = st1;
            *(uint4*)&Bl_sh[cur ^ 1][sl]     = st2;
            *(uint4*)&Bl_sh[cur ^ 1][sl + 8] = st3;
        }
        __syncthreads();
    }

    f32x4 oacc[2][3];
    #pragma unroll
    for (int rf = 0; rf < 2; ++rf)
        #pragma unroll
        for (int cf = 0; cf < 3; ++cf) oacc[rf][cf] = (f32x4){0.f, 0.f, 0.f, 0.f};

    #pragma unroll
    for (int rf = 0; rf < 2; ++rf) {
        #pragma unroll
        for (int cf = 0; cf < 8; ++cf) {
            int col = cf * 16 + rsub;
            #pragma unroll
            for (int r = 0; r < 4; ++r) {
                int rloc = kg * 4 + r;
                float z = fmaxf((acc[rf][cf][r] + biasv[cf] - meanv[cf]) * scalev[cf] + betav[cf], 0.f);
                zw[wid][rloc * 128 + (col ^ ((rloc & 7) << 2))] = packsplit(z);
            }
        }
        const int rloc = rsub;
        const int sw = (rloc & 7) << 2;
        #pragma unroll
        for (int kf = 0; kf < 4; ++kf) {
            int k0 = kf * 32 + kg * 8;
            uint4 ua = *(const uint4*)&zw[wid][rloc * 128 + (k0 ^ sw)];
            uint4 ub = *(const uint4*)&zw[wid][rloc * 128 + ((k0 + 4) ^ sw)];
            unsigned uu[8] = {ua.x, ua.y, ua.z, ua.w, ub.x, ub.y, ub.z, ub.w};
            short8 zh, zl;
            #pragma unroll
            for (int j = 0; j < 8; ++j) {
                zh[j] = (short)(uu[j] >> 16);
                zl[j] = (short)(uu[j] & 0xffffu);
            }
            #pragma unroll
            for (int cf = 0; cf < 3; ++cf) {
                int bidx = ((cf * 4 + kf) * 64 + lane) * 8;
                short8 wh = *(const short8*)(W1hi + bidx);
                short8 wl = *(const short8*)(W1lo + bidx);
                oacc[rf][cf] = __builtin_amdgcn_mfma_f32_16x16x32_bf16(zh, wh, oacc[rf][cf], 0, 0, 0);
                oacc[rf][cf] = __builtin_amdgcn_mfma_f32_16x16x32_bf16(zl, wh, oacc[rf][cf], 0, 0, 0);
                oacc[rf][cf] = __builtin_amdgcn_mfma_f32_16x16x32_bf16(zh, wl, oacc[rf][cf], 0, 0, 0);
            }
        }
    }

    #pragma unroll
    for (int rf = 0; rf < 2; ++rf)
        #pragma unroll
        for (int cf = 0; cf < 3; ++cf) {
            int col = cf * 16 + rsub;
            if (col < 47) {
                float bb = b1[col];
                #pragma unroll
                for (int r = 0; r < 4; ++r) {
                    int row = row0 + rf * 16 + kg * 4 + r;
                    if (row < M) out[(size_t)row * 47 + col] = oacc[rf][cf][r] + bb;
                }
            }
        }
}

// ---------------------------------------------------------------------------
extern "C" void kernel_launch(void* const* d_in, const int* in_sizes, int n_in,
                              void* d_out, int out_size, void* d_ws, size_t ws_size,
                              hipStream_t stream) {
    const float* feat     = (const float*)d_in[0];
    const int*   src      = (const int*)d_in[1];
    const int*   dst      = (const int*)d_in[2];
    const float* enc_W    = (const float*)d_in[3];
    const float* enc_bias = (const float*)d_in[4];
    const float* bn_gamma = (const float*)d_in[5];
    const float* bn_beta  = (const float*)d_in[6];
    const float* bn_mean  = (const float*)d_in[7];
    const float* bn_var   = (const float*)d_in[8];
    const float* cls_W0   = (const float*)d_in[9];
    const float* cls_b0   = (const float*)d_in[10];
    const float* cls_g0   = (const float*)d_in[11];
    const float* cls_be0  = (const float*)d_in[12];
    const float* cls_m0   = (const float*)d_in[13];
    const float* cls_v0   = (const float*)d_in[14];
    const float* cls_W1   = (const float*)d_in[15];
    const float* cls_b1   = (const float*)d_in[16];
    float* out = (float*)d_out;

    const int N_ = in_sizes[0] / 128;
    const int E_ = in_sizes[1];
    const int cscCap = E_ + 7 * N_ + 64;   // padded-CSC capacity (pad to 8)

    char* p = (char*)d_ws;
    auto alloc = [&](size_t bytes) {
        char* r = p;
        p += (bytes + 255) & ~(size_t)255;
        return r;
    };
    __half* h_b = (__half*)alloc((size_t)(N_ + 1) * 128 * 2);  // +1 zero row for pads
    unsigned* hl[4];
    for (int i = 0; i < 4; ++i) hl[i] = (unsigned*)alloc((size_t)N_ * 128 * 4);
    float* norm_src = (float*)alloc((size_t)NN2 * 4);
    float* norm_dst = (float*)alloc((size_t)NN2 * 4);
    int* pdeg   = (int*)alloc((size_t)NN2 * 4);
    int* offs   = (int*)alloc((size_t)(N_ + 1) * 4);
    int* csc    = (int*)alloc((size_t)cscCap * 4);
    int* bsums  = (int*)alloc(256 * 4);
    unsigned* histW = (unsigned*)alloc((size_t)2 * HB * HRANGE * 4);
    unsigned short* bp16 = (unsigned short*)alloc((size_t)HB * NN2 * 2);
    short* encBhi = (short*)alloc(4 * 16384 * 2);
    short* encBlo = (short*)alloc(4 * 16384 * 2);
    short* clsBhi = (short*)alloc(65536 * 2);
    short* clsBlo = (short*)alloc(65536 * 2);
    short* w1hi   = (short*)alloc(6144 * 2);
    short* w1lo   = (short*)alloc(6144 * 2);

    const int EperB = (E_ + HB - 1) / HB;
    const int nb = (N_ + 1023) / 1024;

    hipMemsetAsync(h_b + (size_t)N_ * 128, 0, 256, stream);   // zero row for pads

    hist_kernel<<<2 * HB, 1024, 0, stream>>>(src, dst, histW, E_, EperB);
    merge_kernel<<<(NN2 + 255) / 256, 256, 0, stream>>>(
        (const unsigned short*)histW, pdeg, bp16, norm_src, norm_dst, N_);
    scan_partial_kernel<<<nb, 256, 0, stream>>>(pdeg, bsums, N_);
    scan_bsums_kernel<<<1, 64, 0, stream>>>(bsums, offs, nb, N_);
    scan_final_kernel<<<nb, 256, 0, stream>>>(pdeg, bsums, offs, N_);
    fill_pad_kernel<<<(cscCap / 4 + 255) / 256, 256, 0, stream>>>(csc, cscCap, N_);
    fill_kernel<<<HB, 1024, 0, stream>>>(src, dst, offs, bp16, csc, E_, EperB);

    pack_all_kernel<<<(16384 + 768 + 255) / 256, 256, 0, stream>>>(
        enc_W, cls_W0, cls_W1, encBhi, encBlo, clsBhi, clsBlo, w1hi, w1lo);

    const int gblocks = (N_ + 127) / 128;
    const int agg_blocks = (N_ + 7) / 8;   // 4 waves/block, 2 nodes/wave

    for (int i = 0; i < 4; ++i) {
        if (i == 0)
            mfma_gemm_kernel<false><<<gblocks, 256, 0, stream>>>(
                feat, encBhi, encBlo, norm_src, h_b, N_);
        else
            mfma_gemm_kernel<true><<<gblocks, 256, 0, stream>>>(
                hl[i - 1], encBhi + i * 16384, encBlo + i * 16384, norm_src, h_b, N_);
        aggregate_kernel<<<agg_blocks, 256, 0, stream>>>(
            h_b, offs, csc, norm_dst,
            (i == 3) ? enc_bias : nullptr,
            bn_gamma + i * 128, bn_beta + i * 128, bn_mean + i * 128, bn_var + i * 128,
            hl[i], N_);
    }
    classifier_kernel<<<gblocks, 256, 0, stream>>>(
        hl[0], hl[1], hl[2], hl[3], clsBhi, clsBlo, w1hi, w1lo, cls_b0,
        cls_g0, cls_be0, cls_m0, cls_v0, cls_b1, out, N_);
}

// Round 15
// 303.220 us; speedup vs baseline: 1.1875x; 1.1875x over previous
//
#include <hip/hip_runtime.h>
#include <hip/hip_bf16.h>
#include <hip/hip_fp16.h>

#define EPS 1e-5f
#define HB 128         // histogram/fill blocks (EperB = 6250 < 2^16)
#define HRANGE 25600   // packed u16-pair counters: covers 51200 nodes in 100KB
#define NN2 51200      // 2*HRANGE >= N

typedef __attribute__((ext_vector_type(8))) short short8;
typedef __attribute__((ext_vector_type(4))) float f32x4;

__device__ __forceinline__ unsigned short f2bf_rn(float f) {
    unsigned u = __builtin_bit_cast(unsigned, f);
    u += 0x7fffu + ((u >> 16) & 1u);
    return (unsigned short)(u >> 16);
}
__device__ __forceinline__ float bf2f(unsigned short h) {
    return __builtin_bit_cast(float, (unsigned)h << 16);
}
// pack fp32 -> (bf16 hi | bf16 lo) in one u32
__device__ __forceinline__ unsigned packsplit(float x) {
    unsigned short h = f2bf_rn(x);
    unsigned short l = f2bf_rn(x - bf2f(h));
    return ((unsigned)h << 16) | l;
}

// ---------------------------------------------------------------------------
// K1: per-block LDS histograms (u16-packed pairs, full node range).
// 2*HB blocks: [0,HB) histogram dst, [HB,2HB) histogram src — one edge pass
// per block, all CUs busy. No global atomics.
__global__ __launch_bounds__(1024) void hist_kernel(
    const int* __restrict__ src, const int* __restrict__ dst,
    unsigned* __restrict__ histW, int E, int EperB) {
    __shared__ unsigned cnt[HRANGE];
    const int bb = blockIdx.x;
    const int arr = (bb >= HB) ? 1 : 0;
    const int b = arr ? (bb - HB) : bb;
    const int tid = threadIdx.x;
    const int* a = arr ? src : dst;
    const long e0 = (long)b * EperB;
    const long e1 = min(e0 + (long)EperB, (long)E);
    for (int j = tid; j < HRANGE; j += 1024) cnt[j] = 0;
    __syncthreads();
    for (long e = e0 + tid; e < e1; e += 1024) {
        int v = a[e];
        atomicAdd(&cnt[v >> 1], 1u << ((v & 1) << 4));
    }
    __syncthreads();
    unsigned* o = histW + ((size_t)(arr * HB + b)) * HRANGE;
    for (int j = tid; j < HRANGE; j += 1024) o[j] = cnt[j];
}

// K2: merge per-block hists -> padded degree (multiple of 16), norms, bp16 prefix
__global__ __launch_bounds__(256) void merge_kernel(
    const unsigned short* __restrict__ hist16, int* __restrict__ pdeg,
    unsigned short* __restrict__ bp16, float* __restrict__ nsrc,
    float* __restrict__ ndst, int N) {
    int n = blockIdx.x * blockDim.x + threadIdx.x;
    if (n >= NN2) return;
    unsigned s = 0;
    #pragma unroll 8
    for (int b = 0; b < HB; ++b) {
        unsigned c = hist16[(size_t)b * NN2 + n];
        bp16[(size_t)b * NN2 + n] = (unsigned short)s;
        s += c;
    }
    unsigned s2 = 0;
    #pragma unroll 8
    for (int b = 0; b < HB; ++b) s2 += hist16[(size_t)(HB + b) * NN2 + n];
    if (n < N) {
        pdeg[n] = (int)((s + 15u) & ~15u);   // pad to multiple of 16 (pads -> zero row)
        ndst[n] = rsqrtf((float)max((int)s, 1));
        nsrc[n] = rsqrtf((float)max((int)s2, 1));
    }
}

// ---------------------------------------------------------------------------
// Multi-block exclusive scan of padded degrees -> CSC offsets (all 16-aligned)
__global__ __launch_bounds__(256) void scan_partial_kernel(const int* __restrict__ deg,
                                                           int* __restrict__ bsums, int n) {
    __shared__ int wsum[4];
    const int tid = threadIdx.x, lane = tid & 63, wid = tid >> 6;
    const int i0 = blockIdx.x * 1024 + tid * 4;
    int s = 0;
    if (i0 + 3 < n) {
        int4 v = *(const int4*)(deg + i0);
        s = v.x + v.y + v.z + v.w;
    } else {
        for (int j = 0; j < 4; ++j) if (i0 + j < n) s += deg[i0 + j];
    }
    #pragma unroll
    for (int off = 32; off >= 1; off >>= 1) s += __shfl_down(s, off, 64);
    if (lane == 0) wsum[wid] = s;
    __syncthreads();
    if (tid == 0) bsums[blockIdx.x] = wsum[0] + wsum[1] + wsum[2] + wsum[3];
}

__global__ __launch_bounds__(64) void scan_bsums_kernel(int* __restrict__ bsums,
                                                        int* __restrict__ offs, int nb, int n) {
    int lane = threadIdx.x;
    int v = (lane < nb) ? bsums[lane] : 0;
    int x = v;
    #pragma unroll
    for (int off = 1; off < 64; off <<= 1) {
        int t = __shfl_up(x, off, 64);
        if (lane >= off) x += t;
    }
    if (lane < nb) bsums[lane] = x - v;
    if (lane == 63) offs[n] = x;
}

__global__ __launch_bounds__(256) void scan_final_kernel(const int* __restrict__ deg,
                                                         const int* __restrict__ bsums,
                                                         int* __restrict__ offs, int n) {
    __shared__ int wsum[4];
    const int tid = threadIdx.x, lane = tid & 63, wid = tid >> 6;
    const int i0 = blockIdx.x * 1024 + tid * 4;
    int d0 = 0, d1 = 0, d2 = 0, d3 = 0;
    if (i0 + 3 < n) {
        int4 v = *(const int4*)(deg + i0);
        d0 = v.x; d1 = v.y; d2 = v.z; d3 = v.w;
    } else {
        if (i0 + 0 < n) d0 = deg[i0 + 0];
        if (i0 + 1 < n) d1 = deg[i0 + 1];
        if (i0 + 2 < n) d2 = deg[i0 + 2];
        if (i0 + 3 < n) d3 = deg[i0 + 3];
    }
    int s = d0 + d1 + d2 + d3;
    int x = s;
    #pragma unroll
    for (int off = 1; off < 64; off <<= 1) {
        int t = __shfl_up(x, off, 64);
        if (lane >= off) x += t;
    }
    if (lane == 63) wsum[wid] = x;
    __syncthreads();
    int wpre = 0;
    #pragma unroll
    for (int w = 0; w < 4; ++w) if (w < wid) wpre += wsum[w];
    int base = bsums[blockIdx.x] + wpre + (x - s);
    if (i0 + 0 < n) offs[i0 + 0] = base;
    if (i0 + 1 < n) offs[i0 + 1] = base + d0;
    if (i0 + 2 < n) offs[i0 + 2] = base + d0 + d1;
    if (i0 + 3 < n) offs[i0 + 3] = base + d0 + d1 + d2;
}

// K3d: pre-fill csc pad slots with node index N (the zero row)
__global__ void fill_pad_kernel(int* __restrict__ csc, int total, int N) {
    int i = blockIdx.x * blockDim.x + threadIdx.x;
    int o = i * 4;
    if (o + 3 < total) {
        *(int4*)(csc + o) = make_int4(N, N, N, N);
    } else {
        for (int j = 0; j < 4 && o + j < total; ++j) csc[o + j] = N;
    }
}

// K4: single-pass CSC fill. LDS u16-packed local-rank cursors;
// csc position = offs[d] + bp16[b][d] + local_rank. No global atomics.
__global__ __launch_bounds__(1024) void fill_kernel(
    const int* __restrict__ src, const int* __restrict__ dst,
    const int* __restrict__ offs, const unsigned short* __restrict__ bp16,
    int* __restrict__ csc, int E, int EperB) {
    __shared__ unsigned cur[HRANGE];
    const int b = blockIdx.x, tid = threadIdx.x;
    const long e0 = (long)b * EperB;
    const long e1 = min(e0 + (long)EperB, (long)E);
    for (int j = tid; j < HRANGE; j += 1024) cur[j] = 0;
    __syncthreads();
    const unsigned short* bprow = bp16 + (size_t)b * NN2;
    for (long e = e0 + tid; e < e1; e += 1024) {
        int d = dst[e];
        int sh = (d & 1) << 4;
        unsigned old = atomicAdd(&cur[d >> 1], 1u << sh);
        unsigned rank = (old >> sh) & 0xffffu;
        unsigned p = (unsigned)offs[d] + (unsigned)bprow[d] + rank;
        csc[p] = src[e];
    }
}

// ---------------------------------------------------------------------------
// pack helper: one thread packs 8 elems of one MFMA fragment (cf-major order).
__device__ __forceinline__ void pack_frag(
    const float* __restrict__ B, short* __restrict__ hi, short* __restrict__ lo,
    int K, int NCF, int strideB, int ncols, int t) {
    int KF = K >> 5;
    int lane = t & 63;
    int fid = t >> 6;
    int cf = fid / KF;
    int kf = fid % KF;
    int col = cf * 16 + (lane & 15);
    int k0 = kf * 32 + (lane >> 4) * 8;
    int o = t * 8;
    #pragma unroll
    for (int j = 0; j < 8; ++j) {
        float x = (col < ncols) ? B[(size_t)(k0 + j) * strideB + col] : 0.f;
        unsigned short h = f2bf_rn(x);
        hi[o + j] = (short)h;
        lo[o + j] = (short)f2bf_rn(x - bf2f(h));
    }
}

// Kp: all weight packing in ONE launch.
__global__ __launch_bounds__(256) void pack_all_kernel(
    const float* __restrict__ enc_W, const float* __restrict__ cls_W0,
    const float* __restrict__ cls_W1,
    short* __restrict__ encBhi, short* __restrict__ encBlo,
    short* __restrict__ clsBhi, short* __restrict__ clsBlo,
    short* __restrict__ w1hi, short* __restrict__ w1lo) {
    int t = blockIdx.x * blockDim.x + threadIdx.x;
    if (t < 8192) {
        int i = t >> 11, tt = t & 2047;
        pack_frag(enc_W + (size_t)i * 128 * 128, encBhi + i * 16384, encBlo + i * 16384,
                  128, 8, 128, 128, tt);
    } else if (t < 16384) {
        pack_frag(cls_W0, clsBhi, clsBlo, 512, 8, 128, 128, t - 8192);
    } else if (t < 16384 + 768) {
        pack_frag(cls_W1, w1hi, w1lo, 128, 3, 47, 47, t - 16384);
    }
}

// ---------------------------------------------------------------------------
// K5: MFMA GEMM  C[M,128] (fp16) = norm_src_row * (A[M,128] @ B[128,128])
// B staged whole in LDS (64KB/block, shared by 4 waves). 32 rows/wave.
template<bool PACKED>
__global__ __launch_bounds__(256) void mfma_gemm_kernel(
    const void* __restrict__ Av, const short* __restrict__ Bhi, const short* __restrict__ Blo,
    const float* __restrict__ nsrc, __half* __restrict__ C, int M) {
    __shared__ short Bh_sh[16384];   // 32 KB
    __shared__ short Bl_sh[16384];   // 32 KB
    const int tid = threadIdx.x;
    const int lane = tid & 63;
    const int wid  = tid >> 6;
    const int row0 = blockIdx.x * 128 + wid * 32;
    const int rsub = lane & 15;
    const int kg   = lane >> 4;

    short8 ahi[2][4], alo[2][4];
    #pragma unroll
    for (int rf = 0; rf < 2; ++rf) {
        const int rowa = min(row0 + rf * 16 + rsub, M - 1);
        #pragma unroll
        for (int kf = 0; kf < 4; ++kf) {
            short8 h, l;
            if (PACKED) {
                const unsigned* ap = (const unsigned*)Av + (size_t)rowa * 128 + kg * 8;
                uint4 u0 = *(const uint4*)(ap + kf * 32);
                uint4 u1 = *(const uint4*)(ap + kf * 32 + 4);
                unsigned uu[8] = {u0.x, u0.y, u0.z, u0.w, u1.x, u1.y, u1.z, u1.w};
                #pragma unroll
                for (int j = 0; j < 8; ++j) {
                    h[j] = (short)(uu[j] >> 16);
                    l[j] = (short)(uu[j] & 0xffffu);
                }
            } else {
                const float* ap = (const float*)Av + (size_t)rowa * 128 + kg * 8;
                float4 v0 = *(const float4*)(ap + kf * 32);
                float4 v1 = *(const float4*)(ap + kf * 32 + 4);
                float v[8] = {v0.x, v0.y, v0.z, v0.w, v1.x, v1.y, v1.z, v1.w};
                #pragma unroll
                for (int j = 0; j < 8; ++j) {
                    unsigned short hb = f2bf_rn(v[j]);
                    h[j] = (short)hb;
                    l[j] = (short)f2bf_rn(v[j] - bf2f(hb));
                }
            }
            ahi[rf][kf] = h; alo[rf][kf] = l;
        }
    }

    #pragma unroll
    for (int i = 0; i < 8; ++i) {
        int o = (tid + i * 256) * 8;
        *(uint4*)&Bh_sh[o] = *(const uint4*)&Bhi[o];
        *(uint4*)&Bl_sh[o] = *(const uint4*)&Blo[o];
    }
    __syncthreads();

    f32x4 acc[2][8];
    #pragma unroll
    for (int rf = 0; rf < 2; ++rf)
        #pragma unroll
        for (int cf = 0; cf < 8; ++cf) acc[rf][cf] = (f32x4){0.f, 0.f, 0.f, 0.f};

    #pragma unroll
    for (int cf = 0; cf < 8; ++cf) {
        #pragma unroll
        for (int kf = 0; kf < 4; ++kf) {
            int o = ((cf * 4 + kf) * 64 + lane) * 8;
            short8 bh = *(const short8*)&Bh_sh[o];
            short8 bl = *(const short8*)&Bl_sh[o];
            #pragma unroll
            for (int rf = 0; rf < 2; ++rf) {
                acc[rf][cf] = __builtin_amdgcn_mfma_f32_16x16x32_bf16(ahi[rf][kf], bh, acc[rf][cf], 0, 0, 0);
                acc[rf][cf] = __builtin_amdgcn_mfma_f32_16x16x32_bf16(alo[rf][kf], bh, acc[rf][cf], 0, 0, 0);
                acc[rf][cf] = __builtin_amdgcn_mfma_f32_16x16x32_bf16(ahi[rf][kf], bl, acc[rf][cf], 0, 0, 0);
            }
        }
    }

    #pragma unroll
    for (int rf = 0; rf < 2; ++rf)
        #pragma unroll
        for (int r = 0; r < 4; ++r) {
            int row = row0 + rf * 16 + kg * 4 + r;
            if (row < M) {
                float sc = nsrc[row];
                __half* cp = C + (size_t)row * 128 + rsub;
                #pragma unroll
                for (int cf = 0; cf < 8; ++cf) cp[cf * 16] = __float2half(acc[rf][cf][r] * sc);
            }
        }
}

// ---------------------------------------------------------------------------
// K6: CSC aggregation (fp16 gather, 16-aligned padded segments, zero-row pads)
// + norm_dst + (bias) + BN + ReLU. Writes packed (bf16hi|bf16lo) u32.
// One wave per dst node; 16 gathers in flight per window. (R13-verified form.)
__global__ __launch_bounds__(256) void aggregate_kernel(
    const __half* __restrict__ hw, const int* __restrict__ offs, const int* __restrict__ csc,
    const float* __restrict__ norm_dst, const float* __restrict__ bias,
    const float* __restrict__ gamma, const float* __restrict__ beta,
    const float* __restrict__ mean, const float* __restrict__ var,
    unsigned* __restrict__ hout, int n) {
    const int lane = threadIdx.x & 63;
    const int gw = (blockIdx.x * blockDim.x + threadIdx.x) >> 6;
    const int nw = (gridDim.x * blockDim.x) >> 6;
    const int c = lane * 2;

    const float sc0 = gamma[c] * rsqrtf(var[c] + EPS);
    const float sc1 = gamma[c + 1] * rsqrtf(var[c + 1] + EPS);
    const float mn0 = mean[c], mn1 = mean[c + 1];
    const float bt0 = beta[c], bt1 = beta[c + 1];
    const float bi0 = bias ? bias[c] : 0.f;
    const float bi1 = bias ? bias[c + 1] : 0.f;

    for (int v = gw; v < n; v += nw) {
        const int e0 = offs[v], e1 = offs[v + 1];   // both multiples of 16
        float2 acc = make_float2(0.f, 0.f);
        for (int e = e0; e < e1; e += 16) {
            int4 ca = *(const int4*)(csc + e);
            int4 cb = *(const int4*)(csc + e + 4);
            int4 cc = *(const int4*)(csc + e + 8);
            int4 cd = *(const int4*)(csc + e + 12);
            float2 p0 = __half22float2(*(const __half2*)(hw + (size_t)ca.x * 128 + c));
            float2 p1 = __half22float2(*(const __half2*)(hw + (size_t)ca.y * 128 + c));
            float2 p2 = __half22float2(*(const __half2*)(hw + (size_t)ca.z * 128 + c));
            float2 p3 = __half22float2(*(const __half2*)(hw + (size_t)ca.w * 128 + c));
            float2 p4 = __half22float2(*(const __half2*)(hw + (size_t)cb.x * 128 + c));
            float2 p5 = __half22float2(*(const __half2*)(hw + (size_t)cb.y * 128 + c));
            float2 p6 = __half22float2(*(const __half2*)(hw + (size_t)cb.z * 128 + c));
            float2 p7 = __half22float2(*(const __half2*)(hw + (size_t)cb.w * 128 + c));
            float2 p8 = __half22float2(*(const __half2*)(hw + (size_t)cc.x * 128 + c));
            float2 p9 = __half22float2(*(const __half2*)(hw + (size_t)cc.y * 128 + c));
            float2 pa = __half22float2(*(const __half2*)(hw + (size_t)cc.z * 128 + c));
            float2 pb = __half22float2(*(const __half2*)(hw + (size_t)cc.w * 128 + c));
            float2 pc = __half22float2(*(const __half2*)(hw + (size_t)cd.x * 128 + c));
            float2 pd = __half22float2(*(const __half2*)(hw + (size_t)cd.y * 128 + c));
            float2 pe = __half22float2(*(const __half2*)(hw + (size_t)cd.z * 128 + c));
            float2 pf = __half22float2(*(const __half2*)(hw + (size_t)cd.w * 128 + c));
            acc.x += (((p0.x + p1.x) + (p2.x + p3.x)) + ((p4.x + p5.x) + (p6.x + p7.x)))
                   + (((p8.x + p9.x) + (pa.x + pb.x)) + ((pc.x + pd.x) + (pe.x + pf.x)));
            acc.y += (((p0.y + p1.y) + (p2.y + p3.y)) + ((p4.y + p5.y) + (p6.y + p7.y)))
                   + (((p8.y + p9.y) + (pa.y + pb.y)) + ((pc.y + pd.y) + (pe.y + pf.y)));
        }
        float nd = norm_dst[v];
        float h0 = fmaxf((acc.x * nd + bi0 - mn0) * sc0 + bt0, 0.f);
        float h1 = fmaxf((acc.y * nd + bi1 - mn1) * sc1 + bt1, 0.f);
        uint2 w = make_uint2(packsplit(h0), packsplit(h1));
        *(uint2*)(hout + (size_t)v * 128 + c) = w;
    }
}

// ---------------------------------------------------------------------------
// K7: fused classifier — R10 structure (empirically best: 40.6us).
// 32 rows/wave, 128-row blocks, dbuf 8KB-chunk staging (cf-major), 64KB LDS.
__global__ __launch_bounds__(256) void classifier_kernel(
    const unsigned* __restrict__ h1, const unsigned* __restrict__ h2,
    const unsigned* __restrict__ h3, const unsigned* __restrict__ h4,
    const short* __restrict__ Bhi, const short* __restrict__ Blo,
    const short* __restrict__ W1hi, const short* __restrict__ W1lo,
    const float* __restrict__ b0,
    const float* __restrict__ g, const float* __restrict__ bt,
    const float* __restrict__ mn, const float* __restrict__ vr,
    const float* __restrict__ b1,
    float* __restrict__ out, int M) {
    __shared__ short Bh_sh[2][4096];   // 2 x 8 KB
    __shared__ short Bl_sh[2][4096];   // 2 x 8 KB
    __shared__ unsigned zw[4][16 * 128];  // 32 KB, wave-private tiles
    const int tid = threadIdx.x, lane = tid & 63, wid = tid >> 6;
    const int rsub = lane & 15;
    const int kg   = lane >> 4;
    const int row0 = blockIdx.x * 128 + wid * 32;
    const unsigned* hb[4] = {h1, h2, h3, h4};

    const int scf = tid >> 5, ssub = tid & 31;
    const int sl = scf * 512 + ssub * 16;

    float biasv[8], scalev[8], meanv[8], betav[8];
    #pragma unroll
    for (int cf = 0; cf < 8; ++cf) {
        int col = cf * 16 + rsub;
        biasv[cf] = b0[col];
        scalev[cf] = g[col] * rsqrtf(vr[col] + EPS);
        meanv[cf] = mn[col];
        betav[cf] = bt[col];
    }

    f32x4 acc[2][8];
    #pragma unroll
    for (int rf = 0; rf < 2; ++rf)
        #pragma unroll
        for (int cf = 0; cf < 8; ++cf) acc[rf][cf] = (f32x4){0.f, 0.f, 0.f, 0.f};

    {   // prologue: stage chunk 0
        size_t goff = ((size_t)(scf * 16 + 0) * 64) * 8 + ssub * 16;
        *(uint4*)&Bh_sh[0][sl]     = *(const uint4*)&Bhi[goff];
        *(uint4*)&Bh_sh[0][sl + 8] = *(const uint4*)&Bhi[goff + 8];
        *(uint4*)&Bl_sh[0][sl]     = *(const uint4*)&Blo[goff];
        *(uint4*)&Bl_sh[0][sl + 8] = *(const uint4*)&Blo[goff + 8];
    }
    __syncthreads();

    const int rowa0 = min(row0 + rsub, M - 1);
    const int rowa1 = min(row0 + 16 + rsub, M - 1);

    for (int kf16 = 0; kf16 < 16; ++kf16) {
        const int cur = kf16 & 1;
        uint4 st0, st1, st2, st3;
        if (kf16 < 15) {
            size_t goff = ((size_t)(scf * 16 + kf16 + 1) * 64) * 8 + ssub * 16;
            st0 = *(const uint4*)&Bhi[goff];
            st1 = *(const uint4*)&Bhi[goff + 8];
            st2 = *(const uint4*)&Blo[goff];
            st3 = *(const uint4*)&Blo[goff + 8];
        }
        short8 ah[2], al[2];
        #pragma unroll
        for (int rf = 0; rf < 2; ++rf) {
            const unsigned* ap = hb[kf16 >> 2] + (size_t)(rf ? rowa1 : rowa0) * 128
                                 + (kf16 & 3) * 32 + kg * 8;
            uint4 u0 = *(const uint4*)(ap);
            uint4 u1 = *(const uint4*)(ap + 4);
            unsigned uu[8] = {u0.x, u0.y, u0.z, u0.w, u1.x, u1.y, u1.z, u1.w};
            #pragma unroll
            for (int j = 0; j < 8; ++j) {
                ah[rf][j] = (short)(uu[j] >> 16);
                al[rf][j] = (short)(uu[j] & 0xffffu);
            }
        }
        #pragma unroll
        for (int cf = 0; cf < 8; ++cf) {
            int o = (cf * 64 + lane) * 8;
            short8 bh = *(const short8*)&Bh_sh[cur][o];
            short8 bl = *(const short8*)&Bl_sh[cur][o];
            #pragma unroll
            for (int rf = 0; rf < 2; ++rf) {
                acc[rf][cf] = __builtin_amdgcn_mfma_f32_16x16x32_bf16(ah[rf], bh, acc[rf][cf], 0, 0, 0);
                acc[rf][cf] = __builtin_amdgcn_mfma_f32_16x16x32_bf16(al[rf], bh, acc[rf][cf], 0, 0, 0);
                acc[rf][cf] = __builtin_amdgcn_mfma_f32_16x16x32_bf16(ah[rf], bl, acc[rf][cf], 0, 0, 0);
            }
        }
        if (kf16 < 15) {
            *(uint4*)&Bh_sh[cur ^ 1][sl]     = st0;
            *(uint4*)&Bh_sh[cur ^ 1][sl + 8] = st1;
            *(uint4*)&Bl_sh[cur ^ 1][sl]     = st2;
            *(uint4*)&Bl_sh[cur ^ 1][sl + 8] = st3;
        }
        __syncthreads();
    }

    f32x4 oacc[2][3];
    #pragma unroll
    for (int rf = 0; rf < 2; ++rf)
        #pragma unroll
        for (int cf = 0; cf < 3; ++cf) oacc[rf][cf] = (f32x4){0.f, 0.f, 0.f, 0.f};

    #pragma unroll
    for (int rf = 0; rf < 2; ++rf) {
        #pragma unroll
        for (int cf = 0; cf < 8; ++cf) {
            int col = cf * 16 + rsub;
            #pragma unroll
            for (int r = 0; r < 4; ++r) {
                int rloc = kg * 4 + r;
                float z = fmaxf((acc[rf][cf][r] + biasv[cf] - meanv[cf]) * scalev[cf] + betav[cf], 0.f);
                zw[wid][rloc * 128 + (col ^ ((rloc & 7) << 2))] = packsplit(z);
            }
        }
        const int rloc = rsub;
        const int sw = (rloc & 7) << 2;
        #pragma unroll
        for (int kf = 0; kf < 4; ++kf) {
            int k0 = kf * 32 + kg * 8;
            uint4 ua = *(const uint4*)&zw[wid][rloc * 128 + (k0 ^ sw)];
            uint4 ub = *(const uint4*)&zw[wid][rloc * 128 + ((k0 + 4) ^ sw)];
            unsigned uu[8] = {ua.x, ua.y, ua.z, ua.w, ub.x, ub.y, ub.z, ub.w};
            short8 zh, zl;
            #pragma unroll
            for (int j = 0; j < 8; ++j) {
                zh[j] = (short)(uu[j] >> 16);
                zl[j] = (short)(uu[j] & 0xffffu);
            }
            #pragma unroll
            for (int cf = 0; cf < 3; ++cf) {
                int bidx = ((cf * 4 + kf) * 64 + lane) * 8;
                short8 wh = *(const short8*)(W1hi + bidx);
                short8 wl = *(const short8*)(W1lo + bidx);
                oacc[rf][cf] = __builtin_amdgcn_mfma_f32_16x16x32_bf16(zh, wh, oacc[rf][cf], 0, 0, 0);
                oacc[rf][cf] = __builtin_amdgcn_mfma_f32_16x16x32_bf16(zl, wh, oacc[rf][cf], 0, 0, 0);
                oacc[rf][cf] = __builtin_amdgcn_mfma_f32_16x16x32_bf16(zh, wl, oacc[rf][cf], 0, 0, 0);
            }
        }
    }

    #pragma unroll
    for (int rf = 0; rf < 2; ++rf)
        #pragma unroll
        for (int cf = 0; cf < 3; ++cf) {
            int col = cf * 16 + rsub;
            if (col < 47) {
                float bb = b1[col];
                #pragma unroll
                for (int r = 0; r < 4; ++r) {
                    int row = row0 + rf * 16 + kg * 4 + r;
                    if (row < M) out[(size_t)row * 47 + col] = oacc[rf][cf][r] + bb;
                }
            }
        }
}

// ---------------------------------------------------------------------------
extern "C" void kernel_launch(void* const* d_in, const int* in_sizes, int n_in,
                              void* d_out, int out_size, void* d_ws, size_t ws_size,
                              hipStream_t stream) {
    const float* feat     = (const float*)d_in[0];
    const int*   src      = (const int*)d_in[1];
    const int*   dst      = (const int*)d_in[2];
    const float* enc_W    = (const float*)d_in[3];
    const float* enc_bias = (const float*)d_in[4];
    const float* bn_gamma = (const float*)d_in[5];
    const float* bn_beta  = (const float*)d_in[6];
    const float* bn_mean  = (const float*)d_in[7];
    const float* bn_var   = (const float*)d_in[8];
    const float* cls_W0   = (const float*)d_in[9];
    const float* cls_b0   = (const float*)d_in[10];
    const float* cls_g0   = (const float*)d_in[11];
    const float* cls_be0  = (const float*)d_in[12];
    const float* cls_m0   = (const float*)d_in[13];
    const float* cls_v0   = (const float*)d_in[14];
    const float* cls_W1   = (const float*)d_in[15];
    const float* cls_b1   = (const float*)d_in[16];
    float* out = (float*)d_out;

    const int N_ = in_sizes[0] / 128;
    const int E_ = in_sizes[1];
    const int cscCap = E_ + 15 * N_ + 64;   // padded-CSC capacity (pad to 16)

    char* p = (char*)d_ws;
    auto alloc = [&](size_t bytes) {
        char* r = p;
        p += (bytes + 255) & ~(size_t)255;
        return r;
    };
    __half* h_b = (__half*)alloc((size_t)(N_ + 1) * 128 * 2);  // +1 zero row for pads
    unsigned* hl[4];
    for (int i = 0; i < 4; ++i) hl[i] = (unsigned*)alloc((size_t)N_ * 128 * 4);
    float* norm_src = (float*)alloc((size_t)NN2 * 4);
    float* norm_dst = (float*)alloc((size_t)NN2 * 4);
    int* pdeg   = (int*)alloc((size_t)NN2 * 4);
    int* offs   = (int*)alloc((size_t)(N_ + 1) * 4);
    int* csc    = (int*)alloc((size_t)cscCap * 4);
    int* bsums  = (int*)alloc(256 * 4);
    unsigned* histW = (unsigned*)alloc((size_t)2 * HB * HRANGE * 4);
    unsigned short* bp16 = (unsigned short*)alloc((size_t)HB * NN2 * 2);
    short* encBhi = (short*)alloc(4 * 16384 * 2);
    short* encBlo = (short*)alloc(4 * 16384 * 2);
    short* clsBhi = (short*)alloc(65536 * 2);
    short* clsBlo = (short*)alloc(65536 * 2);
    short* w1hi   = (short*)alloc(6144 * 2);
    short* w1lo   = (short*)alloc(6144 * 2);

    const int EperB = (E_ + HB - 1) / HB;
    const int nb = (N_ + 1023) / 1024;

    hipMemsetAsync(h_b + (size_t)N_ * 128, 0, 256, stream);   // zero row for pads

    hist_kernel<<<2 * HB, 1024, 0, stream>>>(src, dst, histW, E_, EperB);
    merge_kernel<<<(NN2 + 255) / 256, 256, 0, stream>>>(
        (const unsigned short*)histW, pdeg, bp16, norm_src, norm_dst, N_);
    scan_partial_kernel<<<nb, 256, 0, stream>>>(pdeg, bsums, N_);
    scan_bsums_kernel<<<1, 64, 0, stream>>>(bsums, offs, nb, N_);
    scan_final_kernel<<<nb, 256, 0, stream>>>(pdeg, bsums, offs, N_);
    fill_pad_kernel<<<(cscCap / 4 + 255) / 256, 256, 0, stream>>>(csc, cscCap, N_);
    fill_kernel<<<HB, 1024, 0, stream>>>(src, dst, offs, bp16, csc, E_, EperB);

    pack_all_kernel<<<(16384 + 768 + 255) / 256, 256, 0, stream>>>(
        enc_W, cls_W0, cls_W1, encBhi, encBlo, clsBhi, clsBlo, w1hi, w1lo);

    const int gblocks = (N_ + 127) / 128;
    const int agg_blocks = (N_ + 3) / 4;

    for (int i = 0; i < 4; ++i) {
        if (i == 0)
            mfma_gemm_kernel<false><<<gblocks, 256, 0, stream>>>(
                feat, encBhi, encBlo, norm_src, h_b, N_);
        else
            mfma_gemm_kernel<true><<<gblocks, 256, 0, stream>>>(
                hl[i - 1], encBhi + i * 16384, encBlo + i * 16384, norm_src, h_b, N_);
        aggregate_kernel<<<agg_blocks, 256, 0, stream>>>(
            h_b, offs, csc, norm_dst,
            (i == 3) ? enc_bias : nullptr,
            bn_gamma + i * 128, bn_beta + i * 128, bn_mean + i * 128, bn_var + i * 128,
            hl[i], N_);
    }
    classifier_kernel<<<gblocks, 256, 0, stream>>>(
        hl[0], hl[1], hl[2], hl[3], clsBhi, clsBlo, w1hi, w1lo, cls_b0,
        cls_g0, cls_be0, cls_m0, cls_v0, cls_b1, out, N_);
}

// Round 16
// 300.225 us; speedup vs baseline: 1.1994x; 1.0100x over previous
//
#include <hip/hip_runtime.h>
#include <hip/hip_bf16.h>
#include <hip/hip_fp16.h>

#define EPS 1e-5f
#define HB 128         // histogram/fill blocks (EperB = 6250 < 2^16)
#define HRANGE 25600   // packed u16-pair counters: covers 51200 nodes in 100KB
#define NN2 51200      // 2*HRANGE >= N

typedef __attribute__((ext_vector_type(8))) short short8;
typedef __attribute__((ext_vector_type(4))) float f32x4;

__device__ __forceinline__ unsigned short f2bf_rn(float f) {
    unsigned u = __builtin_bit_cast(unsigned, f);
    u += 0x7fffu + ((u >> 16) & 1u);
    return (unsigned short)(u >> 16);
}
__device__ __forceinline__ float bf2f(unsigned short h) {
    return __builtin_bit_cast(float, (unsigned)h << 16);
}
// pack fp32 -> (bf16 hi | bf16 lo) in one u32
__device__ __forceinline__ unsigned packsplit(float x) {
    unsigned short h = f2bf_rn(x);
    unsigned short l = f2bf_rn(x - bf2f(h));
    return ((unsigned)h << 16) | l;
}

// ---------------------------------------------------------------------------
// K1: per-block LDS histograms (u16-packed pairs, full node range).
// 2*HB blocks: [0,HB) histogram dst, [HB,2HB) histogram src.
__global__ __launch_bounds__(1024) void hist_kernel(
    const int* __restrict__ src, const int* __restrict__ dst,
    unsigned* __restrict__ histW, int E, int EperB) {
    __shared__ unsigned cnt[HRANGE];
    const int bb = blockIdx.x;
    const int arr = (bb >= HB) ? 1 : 0;
    const int b = arr ? (bb - HB) : bb;
    const int tid = threadIdx.x;
    const int* a = arr ? src : dst;
    const long e0 = (long)b * EperB;
    const long e1 = min(e0 + (long)EperB, (long)E);
    for (int j = tid; j < HRANGE; j += 1024) cnt[j] = 0;
    __syncthreads();
    for (long e = e0 + tid; e < e1; e += 1024) {
        int v = a[e];
        atomicAdd(&cnt[v >> 1], 1u << ((v & 1) << 4));
    }
    __syncthreads();
    unsigned* o = histW + ((size_t)(arr * HB + b)) * HRANGE;
    for (int j = tid; j < HRANGE; j += 1024) o[j] = cnt[j];
}

// K2: merge per-block hists -> padded degree (multiple of 16), norms, bp16 prefix
__global__ __launch_bounds__(256) void merge_kernel(
    const unsigned short* __restrict__ hist16, int* __restrict__ pdeg,
    unsigned short* __restrict__ bp16, float* __restrict__ nsrc,
    float* __restrict__ ndst, int N) {
    int n = blockIdx.x * blockDim.x + threadIdx.x;
    if (n >= NN2) return;
    unsigned s = 0;
    #pragma unroll 8
    for (int b = 0; b < HB; ++b) {
        unsigned c = hist16[(size_t)b * NN2 + n];
        bp16[(size_t)b * NN2 + n] = (unsigned short)s;
        s += c;
    }
    unsigned s2 = 0;
    #pragma unroll 8
    for (int b = 0; b < HB; ++b) s2 += hist16[(size_t)(HB + b) * NN2 + n];
    if (n < N) {
        pdeg[n] = (int)((s + 15u) & ~15u);   // pad to multiple of 16
        ndst[n] = rsqrtf((float)max((int)s, 1));
        nsrc[n] = rsqrtf((float)max((int)s2, 1));
    }
}

// ---------------------------------------------------------------------------
// Multi-block exclusive scan of padded degrees -> CSC offsets (16-aligned)
__global__ __launch_bounds__(256) void scan_partial_kernel(const int* __restrict__ deg,
                                                           int* __restrict__ bsums, int n) {
    __shared__ int wsum[4];
    const int tid = threadIdx.x, lane = tid & 63, wid = tid >> 6;
    const int i0 = blockIdx.x * 1024 + tid * 4;
    int s = 0;
    if (i0 + 3 < n) {
        int4 v = *(const int4*)(deg + i0);
        s = v.x + v.y + v.z + v.w;
    } else {
        for (int j = 0; j < 4; ++j) if (i0 + j < n) s += deg[i0 + j];
    }
    #pragma unroll
    for (int off = 32; off >= 1; off >>= 1) s += __shfl_down(s, off, 64);
    if (lane == 0) wsum[wid] = s;
    __syncthreads();
    if (tid == 0) bsums[blockIdx.x] = wsum[0] + wsum[1] + wsum[2] + wsum[3];
}

__global__ __launch_bounds__(64) void scan_bsums_kernel(int* __restrict__ bsums,
                                                        int* __restrict__ offs, int nb, int n) {
    int lane = threadIdx.x;
    int v = (lane < nb) ? bsums[lane] : 0;
    int x = v;
    #pragma unroll
    for (int off = 1; off < 64; off <<= 1) {
        int t = __shfl_up(x, off, 64);
        if (lane >= off) x += t;
    }
    if (lane < nb) bsums[lane] = x - v;
    if (lane == 63) offs[n] = x;
}

__global__ __launch_bounds__(256) void scan_final_kernel(const int* __restrict__ deg,
                                                         const int* __restrict__ bsums,
                                                         int* __restrict__ offs, int n) {
    __shared__ int wsum[4];
    const int tid = threadIdx.x, lane = tid & 63, wid = tid >> 6;
    const int i0 = blockIdx.x * 1024 + tid * 4;
    int d0 = 0, d1 = 0, d2 = 0, d3 = 0;
    if (i0 + 3 < n) {
        int4 v = *(const int4*)(deg + i0);
        d0 = v.x; d1 = v.y; d2 = v.z; d3 = v.w;
    } else {
        if (i0 + 0 < n) d0 = deg[i0 + 0];
        if (i0 + 1 < n) d1 = deg[i0 + 1];
        if (i0 + 2 < n) d2 = deg[i0 + 2];
        if (i0 + 3 < n) d3 = deg[i0 + 3];
    }
    int s = d0 + d1 + d2 + d3;
    int x = s;
    #pragma unroll
    for (int off = 1; off < 64; off <<= 1) {
        int t = __shfl_up(x, off, 64);
        if (lane >= off) x += t;
    }
    if (lane == 63) wsum[wid] = x;
    __syncthreads();
    int wpre = 0;
    #pragma unroll
    for (int w = 0; w < 4; ++w) if (w < wid) wpre += wsum[w];
    int base = bsums[blockIdx.x] + wpre + (x - s);
    if (i0 + 0 < n) offs[i0 + 0] = base;
    if (i0 + 1 < n) offs[i0 + 1] = base + d0;
    if (i0 + 2 < n) offs[i0 + 2] = base + d0 + d1;
    if (i0 + 3 < n) offs[i0 + 3] = base + d0 + d1 + d2;
}

// K3d: pre-fill csc pad slots with node index N (the zero row)
__global__ void fill_pad_kernel(int* __restrict__ csc, int total, int N) {
    int i = blockIdx.x * blockDim.x + threadIdx.x;
    int o = i * 4;
    if (o + 3 < total) {
        *(int4*)(csc + o) = make_int4(N, N, N, N);
    } else {
        for (int j = 0; j < 4 && o + j < total; ++j) csc[o + j] = N;
    }
}

// K4: single-pass CSC fill. LDS u16-packed local-rank cursors.
__global__ __launch_bounds__(1024) void fill_kernel(
    const int* __restrict__ src, const int* __restrict__ dst,
    const int* __restrict__ offs, const unsigned short* __restrict__ bp16,
    int* __restrict__ csc, int E, int EperB) {
    __shared__ unsigned cur[HRANGE];
    const int b = blockIdx.x, tid = threadIdx.x;
    const long e0 = (long)b * EperB;
    const long e1 = min(e0 + (long)EperB, (long)E);
    for (int j = tid; j < HRANGE; j += 1024) cur[j] = 0;
    __syncthreads();
    const unsigned short* bprow = bp16 + (size_t)b * NN2;
    for (long e = e0 + tid; e < e1; e += 1024) {
        int d = dst[e];
        int sh = (d & 1) << 4;
        unsigned old = atomicAdd(&cur[d >> 1], 1u << sh);
        unsigned rank = (old >> sh) & 0xffffu;
        unsigned p = (unsigned)offs[d] + (unsigned)bprow[d] + rank;
        csc[p] = src[e];
    }
}

// ---------------------------------------------------------------------------
__device__ __forceinline__ void pack_frag(
    const float* __restrict__ B, short* __restrict__ hi, short* __restrict__ lo,
    int K, int NCF, int strideB, int ncols, int t) {
    int KF = K >> 5;
    int lane = t & 63;
    int fid = t >> 6;
    int cf = fid / KF;
    int kf = fid % KF;
    int col = cf * 16 + (lane & 15);
    int k0 = kf * 32 + (lane >> 4) * 8;
    int o = t * 8;
    #pragma unroll
    for (int j = 0; j < 8; ++j) {
        float x = (col < ncols) ? B[(size_t)(k0 + j) * strideB + col] : 0.f;
        unsigned short h = f2bf_rn(x);
        hi[o + j] = (short)h;
        lo[o + j] = (short)f2bf_rn(x - bf2f(h));
    }
}

__global__ __launch_bounds__(256) void pack_all_kernel(
    const float* __restrict__ enc_W, const float* __restrict__ cls_W0,
    const float* __restrict__ cls_W1,
    short* __restrict__ encBhi, short* __restrict__ encBlo,
    short* __restrict__ clsBhi, short* __restrict__ clsBlo,
    short* __restrict__ w1hi, short* __restrict__ w1lo) {
    int t = blockIdx.x * blockDim.x + threadIdx.x;
    if (t < 8192) {
        int i = t >> 11, tt = t & 2047;
        pack_frag(enc_W + (size_t)i * 128 * 128, encBhi + i * 16384, encBlo + i * 16384,
                  128, 8, 128, 128, tt);
    } else if (t < 16384) {
        pack_frag(cls_W0, clsBhi, clsBlo, 512, 8, 128, 128, t - 8192);
    } else if (t < 16384 + 768) {
        pack_frag(cls_W1, w1hi, w1lo, 128, 3, 47, 47, t - 16384);
    }
}

// ---------------------------------------------------------------------------
// K5: MFMA GEMM  C[M,128] (fp16) = norm_src_row * (A[M,128] @ B[128,128])
template<bool PACKED>
__global__ __launch_bounds__(256) void mfma_gemm_kernel(
    const void* __restrict__ Av, const short* __restrict__ Bhi, const short* __restrict__ Blo,
    const float* __restrict__ nsrc, __half* __restrict__ C, int M) {
    __shared__ short Bh_sh[16384];   // 32 KB
    __shared__ short Bl_sh[16384];   // 32 KB
    const int tid = threadIdx.x;
    const int lane = tid & 63;
    const int wid  = tid >> 6;
    const int row0 = blockIdx.x * 128 + wid * 32;
    const int rsub = lane & 15;
    const int kg   = lane >> 4;

    short8 ahi[2][4], alo[2][4];
    #pragma unroll
    for (int rf = 0; rf < 2; ++rf) {
        const int rowa = min(row0 + rf * 16 + rsub, M - 1);
        #pragma unroll
        for (int kf = 0; kf < 4; ++kf) {
            short8 h, l;
            if (PACKED) {
                const unsigned* ap = (const unsigned*)Av + (size_t)rowa * 128 + kg * 8;
                uint4 u0 = *(const uint4*)(ap + kf * 32);
                uint4 u1 = *(const uint4*)(ap + kf * 32 + 4);
                unsigned uu[8] = {u0.x, u0.y, u0.z, u0.w, u1.x, u1.y, u1.z, u1.w};
                #pragma unroll
                for (int j = 0; j < 8; ++j) {
                    h[j] = (short)(uu[j] >> 16);
                    l[j] = (short)(uu[j] & 0xffffu);
                }
            } else {
                const float* ap = (const float*)Av + (size_t)rowa * 128 + kg * 8;
                float4 v0 = *(const float4*)(ap + kf * 32);
                float4 v1 = *(const float4*)(ap + kf * 32 + 4);
                float v[8] = {v0.x, v0.y, v0.z, v0.w, v1.x, v1.y, v1.z, v1.w};
                #pragma unroll
                for (int j = 0; j < 8; ++j) {
                    unsigned short hb = f2bf_rn(v[j]);
                    h[j] = (short)hb;
                    l[j] = (short)f2bf_rn(v[j] - bf2f(hb));
                }
            }
            ahi[rf][kf] = h; alo[rf][kf] = l;
        }
    }

    #pragma unroll
    for (int i = 0; i < 8; ++i) {
        int o = (tid + i * 256) * 8;
        *(uint4*)&Bh_sh[o] = *(const uint4*)&Bhi[o];
        *(uint4*)&Bl_sh[o] = *(const uint4*)&Blo[o];
    }
    __syncthreads();

    f32x4 acc[2][8];
    #pragma unroll
    for (int rf = 0; rf < 2; ++rf)
        #pragma unroll
        for (int cf = 0; cf < 8; ++cf) acc[rf][cf] = (f32x4){0.f, 0.f, 0.f, 0.f};

    #pragma unroll
    for (int cf = 0; cf < 8; ++cf) {
        #pragma unroll
        for (int kf = 0; kf < 4; ++kf) {
            int o = ((cf * 4 + kf) * 64 + lane) * 8;
            short8 bh = *(const short8*)&Bh_sh[o];
            short8 bl = *(const short8*)&Bl_sh[o];
            #pragma unroll
            for (int rf = 0; rf < 2; ++rf) {
                acc[rf][cf] = __builtin_amdgcn_mfma_f32_16x16x32_bf16(ahi[rf][kf], bh, acc[rf][cf], 0, 0, 0);
                acc[rf][cf] = __builtin_amdgcn_mfma_f32_16x16x32_bf16(alo[rf][kf], bh, acc[rf][cf], 0, 0, 0);
                acc[rf][cf] = __builtin_amdgcn_mfma_f32_16x16x32_bf16(ahi[rf][kf], bl, acc[rf][cf], 0, 0, 0);
            }
        }
    }

    #pragma unroll
    for (int rf = 0; rf < 2; ++rf)
        #pragma unroll
        for (int r = 0; r < 4; ++r) {
            int row = row0 + rf * 16 + kg * 4 + r;
            if (row < M) {
                float sc = nsrc[row];
                __half* cp = C + (size_t)row * 128 + rsub;
                #pragma unroll
                for (int cf = 0; cf < 8; ++cf) cp[cf * 16] = __float2half(acc[rf][cf][r] * sc);
            }
        }
}

// ---------------------------------------------------------------------------
// K6: CSC aggregation (fp16 gather, 16-aligned padded segments, zero-row pads)
// + norm_dst + (bias) + BN + ReLU. One wave per dst node. (R13/R15-verified.)
__global__ __launch_bounds__(256) void aggregate_kernel(
    const __half* __restrict__ hw, const int* __restrict__ offs, const int* __restrict__ csc,
    const float* __restrict__ norm_dst, const float* __restrict__ bias,
    const float* __restrict__ gamma, const float* __restrict__ beta,
    const float* __restrict__ mean, const float* __restrict__ var,
    unsigned* __restrict__ hout, int n) {
    const int lane = threadIdx.x & 63;
    const int gw = (blockIdx.x * blockDim.x + threadIdx.x) >> 6;
    const int nw = (gridDim.x * blockDim.x) >> 6;
    const int c = lane * 2;

    const float sc0 = gamma[c] * rsqrtf(var[c] + EPS);
    const float sc1 = gamma[c + 1] * rsqrtf(var[c + 1] + EPS);
    const float mn0 = mean[c], mn1 = mean[c + 1];
    const float bt0 = beta[c], bt1 = beta[c + 1];
    const float bi0 = bias ? bias[c] : 0.f;
    const float bi1 = bias ? bias[c + 1] : 0.f;

    for (int v = gw; v < n; v += nw) {
        const int e0 = offs[v], e1 = offs[v + 1];
        float2 acc = make_float2(0.f, 0.f);
        for (int e = e0; e < e1; e += 16) {
            int4 ca = *(const int4*)(csc + e);
            int4 cb = *(const int4*)(csc + e + 4);
            int4 cc = *(const int4*)(csc + e + 8);
            int4 cd = *(const int4*)(csc + e + 12);
            float2 p0 = __half22float2(*(const __half2*)(hw + (size_t)ca.x * 128 + c));
            float2 p1 = __half22float2(*(const __half2*)(hw + (size_t)ca.y * 128 + c));
            float2 p2 = __half22float2(*(const __half2*)(hw + (size_t)ca.z * 128 + c));
            float2 p3 = __half22float2(*(const __half2*)(hw + (size_t)ca.w * 128 + c));
            float2 p4 = __half22float2(*(const __half2*)(hw + (size_t)cb.x * 128 + c));
            float2 p5 = __half22float2(*(const __half2*)(hw + (size_t)cb.y * 128 + c));
            float2 p6 = __half22float2(*(const __half2*)(hw + (size_t)cb.z * 128 + c));
            float2 p7 = __half22float2(*(const __half2*)(hw + (size_t)cb.w * 128 + c));
            float2 p8 = __half22float2(*(const __half2*)(hw + (size_t)cc.x * 128 + c));
            float2 p9 = __half22float2(*(const __half2*)(hw + (size_t)cc.y * 128 + c));
            float2 pa = __half22float2(*(const __half2*)(hw + (size_t)cc.z * 128 + c));
            float2 pb = __half22float2(*(const __half2*)(hw + (size_t)cc.w * 128 + c));
            float2 pc = __half22float2(*(const __half2*)(hw + (size_t)cd.x * 128 + c));
            float2 pd = __half22float2(*(const __half2*)(hw + (size_t)cd.y * 128 + c));
            float2 pe = __half22float2(*(const __half2*)(hw + (size_t)cd.z * 128 + c));
            float2 pf = __half22float2(*(const __half2*)(hw + (size_t)cd.w * 128 + c));
            acc.x += (((p0.x + p1.x) + (p2.x + p3.x)) + ((p4.x + p5.x) + (p6.x + p7.x)))
                   + (((p8.x + p9.x) + (pa.x + pb.x)) + ((pc.x + pd.x) + (pe.x + pf.x)));
            acc.y += (((p0.y + p1.y) + (p2.y + p3.y)) + ((p4.y + p5.y) + (p6.y + p7.y)))
                   + (((p8.y + p9.y) + (pa.y + pb.y)) + ((pc.y + pd.y) + (pe.y + pf.y)));
        }
        float nd = norm_dst[v];
        float h0 = fmaxf((acc.x * nd + bi0 - mn0) * sc0 + bt0, 0.f);
        float h1 = fmaxf((acc.y * nd + bi1 - mn1) * sc1 + bt1, 0.f);
        uint2 w = make_uint2(packsplit(h0), packsplit(h1));
        *(uint2*)(hout + (size_t)v * 128 + c) = w;
    }
}

// ---------------------------------------------------------------------------
// K7: fused classifier — R10 geometry (32 rows/wave, 128-row blocks, dbuf
// cf-major staging, 64KB LDS) + T14-style A-row prefetch: next kf16's A
// global loads issue before the current MFMA cluster, hiding their latency
// under MFMA + barrier.
__global__ __launch_bounds__(256) void classifier_kernel(
    const unsigned* __restrict__ h1, const unsigned* __restrict__ h2,
    const unsigned* __restrict__ h3, const unsigned* __restrict__ h4,
    const short* __restrict__ Bhi, const short* __restrict__ Blo,
    const short* __restrict__ W1hi, const short* __restrict__ W1lo,
    const float* __restrict__ b0,
    const float* __restrict__ g, const float* __restrict__ bt,
    const float* __restrict__ mn, const float* __restrict__ vr,
    const float* __restrict__ b1,
    float* __restrict__ out, int M) {
    __shared__ short Bh_sh[2][4096];   // 2 x 8 KB
    __shared__ short Bl_sh[2][4096];   // 2 x 8 KB
    __shared__ unsigned zw[4][16 * 128];  // 32 KB, wave-private tiles
    const int tid = threadIdx.x, lane = tid & 63, wid = tid >> 6;
    const int rsub = lane & 15;
    const int kg   = lane >> 4;
    const int row0 = blockIdx.x * 128 + wid * 32;
    const unsigned* hb[4] = {h1, h2, h3, h4};

    const int scf = tid >> 5, ssub = tid & 31;
    const int sl = scf * 512 + ssub * 16;

    float biasv[8], scalev[8], meanv[8], betav[8];
    #pragma unroll
    for (int cf = 0; cf < 8; ++cf) {
        int col = cf * 16 + rsub;
        biasv[cf] = b0[col];
        scalev[cf] = g[col] * rsqrtf(vr[col] + EPS);
        meanv[cf] = mn[col];
        betav[cf] = bt[col];
    }

    f32x4 acc[2][8];
    #pragma unroll
    for (int rf = 0; rf < 2; ++rf)
        #pragma unroll
        for (int cf = 0; cf < 8; ++cf) acc[rf][cf] = (f32x4){0.f, 0.f, 0.f, 0.f};

    {   // prologue: stage chunk 0
        size_t goff = ((size_t)(scf * 16 + 0) * 64) * 8 + ssub * 16;
        *(uint4*)&Bh_sh[0][sl]     = *(const uint4*)&Bhi[goff];
        *(uint4*)&Bh_sh[0][sl + 8] = *(const uint4*)&Bhi[goff + 8];
        *(uint4*)&Bl_sh[0][sl]     = *(const uint4*)&Blo[goff];
        *(uint4*)&Bl_sh[0][sl + 8] = *(const uint4*)&Blo[goff + 8];
    }

    const int rowa0 = min(row0 + rsub, M - 1);
    const int rowa1 = min(row0 + 16 + rsub, M - 1);

    // A prologue: load kf16=0's A rows into registers
    uint4 a0c, a1c, a0n, a1n;   // current/next, rf=0/1 (each uint4 = 4 u32; need 8 -> two uint4 per rf)
    uint4 b0c, b1c, b0n, b1n;   // second halves
    {
        const unsigned* ap0 = hb[0] + (size_t)rowa0 * 128 + kg * 8;
        const unsigned* ap1 = hb[0] + (size_t)rowa1 * 128 + kg * 8;
        a0c = *(const uint4*)(ap0);
        b0c = *(const uint4*)(ap0 + 4);
        a1c = *(const uint4*)(ap1);
        b1c = *(const uint4*)(ap1 + 4);
    }
    __syncthreads();

    for (int kf16 = 0; kf16 < 16; ++kf16) {
        const int cur = kf16 & 1;
        uint4 st0, st1, st2, st3;
        if (kf16 < 15) {
            // B prefetch for LDS chunk kf16+1
            size_t goff = ((size_t)(scf * 16 + kf16 + 1) * 64) * 8 + ssub * 16;
            st0 = *(const uint4*)&Bhi[goff];
            st1 = *(const uint4*)&Bhi[goff + 8];
            st2 = *(const uint4*)&Blo[goff];
            st3 = *(const uint4*)&Blo[goff + 8];
            // A prefetch for iteration kf16+1 (hides under MFMA below)
            const int nk = kf16 + 1;
            const unsigned* ap0 = hb[nk >> 2] + (size_t)rowa0 * 128 + (nk & 3) * 32 + kg * 8;
            const unsigned* ap1 = hb[nk >> 2] + (size_t)rowa1 * 128 + (nk & 3) * 32 + kg * 8;
            a0n = *(const uint4*)(ap0);
            b0n = *(const uint4*)(ap0 + 4);
            a1n = *(const uint4*)(ap1);
            b1n = *(const uint4*)(ap1 + 4);
        }
        // unpack current A registers
        short8 ah[2], al[2];
        {
            unsigned uu0[8] = {a0c.x, a0c.y, a0c.z, a0c.w, b0c.x, b0c.y, b0c.z, b0c.w};
            unsigned uu1[8] = {a1c.x, a1c.y, a1c.z, a1c.w, b1c.x, b1c.y, b1c.z, b1c.w};
            #pragma unroll
            for (int j = 0; j < 8; ++j) {
                ah[0][j] = (short)(uu0[j] >> 16);
                al[0][j] = (short)(uu0[j] & 0xffffu);
                ah[1][j] = (short)(uu1[j] >> 16);
                al[1][j] = (short)(uu1[j] & 0xffffu);
            }
        }
        #pragma unroll
        for (int cf = 0; cf < 8; ++cf) {
            int o = (cf * 64 + lane) * 8;
            short8 bh = *(const short8*)&Bh_sh[cur][o];
            short8 bl = *(const short8*)&Bl_sh[cur][o];
            #pragma unroll
            for (int rf = 0; rf < 2; ++rf) {
                acc[rf][cf] = __builtin_amdgcn_mfma_f32_16x16x32_bf16(ah[rf], bh, acc[rf][cf], 0, 0, 0);
                acc[rf][cf] = __builtin_amdgcn_mfma_f32_16x16x32_bf16(al[rf], bh, acc[rf][cf], 0, 0, 0);
                acc[rf][cf] = __builtin_amdgcn_mfma_f32_16x16x32_bf16(ah[rf], bl, acc[rf][cf], 0, 0, 0);
            }
        }
        if (kf16 < 15) {
            *(uint4*)&Bh_sh[cur ^ 1][sl]     = st0;
            *(uint4*)&Bh_sh[cur ^ 1][sl + 8] = st1;
            *(uint4*)&Bl_sh[cur ^ 1][sl]     = st2;
            *(uint4*)&Bl_sh[cur ^ 1][sl + 8] = st3;
            a0c = a0n; b0c = b0n; a1c = a1n; b1c = b1n;
        }
        __syncthreads();
    }

    f32x4 oacc[2][3];
    #pragma unroll
    for (int rf = 0; rf < 2; ++rf)
        #pragma unroll
        for (int cf = 0; cf < 3; ++cf) oacc[rf][cf] = (f32x4){0.f, 0.f, 0.f, 0.f};

    #pragma unroll
    for (int rf = 0; rf < 2; ++rf) {
        #pragma unroll
        for (int cf = 0; cf < 8; ++cf) {
            int col = cf * 16 + rsub;
            #pragma unroll
            for (int r = 0; r < 4; ++r) {
                int rloc = kg * 4 + r;
                float z = fmaxf((acc[rf][cf][r] + biasv[cf] - meanv[cf]) * scalev[cf] + betav[cf], 0.f);
                zw[wid][rloc * 128 + (col ^ ((rloc & 7) << 2))] = packsplit(z);
            }
        }
        const int rloc = rsub;
        const int sw = (rloc & 7) << 2;
        #pragma unroll
        for (int kf = 0; kf < 4; ++kf) {
            int k0 = kf * 32 + kg * 8;
            uint4 ua = *(const uint4*)&zw[wid][rloc * 128 + (k0 ^ sw)];
            uint4 ub = *(const uint4*)&zw[wid][rloc * 128 + ((k0 + 4) ^ sw)];
            unsigned uu[8] = {ua.x, ua.y, ua.z, ua.w, ub.x, ub.y, ub.z, ub.w};
            short8 zh, zl;
            #pragma unroll
            for (int j = 0; j < 8; ++j) {
                zh[j] = (short)(uu[j] >> 16);
                zl[j] = (short)(uu[j] & 0xffffu);
            }
            #pragma unroll
            for (int cf = 0; cf < 3; ++cf) {
                int bidx = ((cf * 4 + kf) * 64 + lane) * 8;
                short8 wh = *(const short8*)(W1hi + bidx);
                short8 wl = *(const short8*)(W1lo + bidx);
                oacc[rf][cf] = __builtin_amdgcn_mfma_f32_16x16x32_bf16(zh, wh, oacc[rf][cf], 0, 0, 0);
                oacc[rf][cf] = __builtin_amdgcn_mfma_f32_16x16x32_bf16(zl, wh, oacc[rf][cf], 0, 0, 0);
                oacc[rf][cf] = __builtin_amdgcn_mfma_f32_16x16x32_bf16(zh, wl, oacc[rf][cf], 0, 0, 0);
            }
        }
    }

    #pragma unroll
    for (int rf = 0; rf < 2; ++rf)
        #pragma unroll
        for (int cf = 0; cf < 3; ++cf) {
            int col = cf * 16 + rsub;
            if (col < 47) {
                float bb = b1[col];
                #pragma unroll
                for (int r = 0; r < 4; ++r) {
                    int row = row0 + rf * 16 + kg * 4 + r;
                    if (row < M) out[(size_t)row * 47 + col] = oacc[rf][cf][r] + bb;
                }
            }
        }
}

// ---------------------------------------------------------------------------
extern "C" void kernel_launch(void* const* d_in, const int* in_sizes, int n_in,
                              void* d_out, int out_size, void* d_ws, size_t ws_size,
                              hipStream_t stream) {
    const float* feat     = (const float*)d_in[0];
    const int*   src      = (const int*)d_in[1];
    const int*   dst      = (const int*)d_in[2];
    const float* enc_W    = (const float*)d_in[3];
    const float* enc_bias = (const float*)d_in[4];
    const float* bn_gamma = (const float*)d_in[5];
    const float* bn_beta  = (const float*)d_in[6];
    const float* bn_mean  = (const float*)d_in[7];
    const float* bn_var   = (const float*)d_in[8];
    const float* cls_W0   = (const float*)d_in[9];
    const float* cls_b0   = (const float*)d_in[10];
    const float* cls_g0   = (const float*)d_in[11];
    const float* cls_be0  = (const float*)d_in[12];
    const float* cls_m0   = (const float*)d_in[13];
    const float* cls_v0   = (const float*)d_in[14];
    const float* cls_W1   = (const float*)d_in[15];
    const float* cls_b1   = (const float*)d_in[16];
    float* out = (float*)d_out;

    const int N_ = in_sizes[0] / 128;
    const int E_ = in_sizes[1];
    const int cscCap = E_ + 15 * N_ + 64;   // padded-CSC capacity (pad to 16)

    char* p = (char*)d_ws;
    auto alloc = [&](size_t bytes) {
        char* r = p;
        p += (bytes + 255) & ~(size_t)255;
        return r;
    };
    __half* h_b = (__half*)alloc((size_t)(N_ + 1) * 128 * 2);  // +1 zero row for pads
    unsigned* hl[4];
    for (int i = 0; i < 4; ++i) hl[i] = (unsigned*)alloc((size_t)N_ * 128 * 4);
    float* norm_src = (float*)alloc((size_t)NN2 * 4);
    float* norm_dst = (float*)alloc((size_t)NN2 * 4);
    int* pdeg   = (int*)alloc((size_t)NN2 * 4);
    int* offs   = (int*)alloc((size_t)(N_ + 1) * 4);
    int* csc    = (int*)alloc((size_t)cscCap * 4);
    int* bsums  = (int*)alloc(256 * 4);
    unsigned* histW = (unsigned*)alloc((size_t)2 * HB * HRANGE * 4);
    unsigned short* bp16 = (unsigned short*)alloc((size_t)HB * NN2 * 2);
    short* encBhi = (short*)alloc(4 * 16384 * 2);
    short* encBlo = (short*)alloc(4 * 16384 * 2);
    short* clsBhi = (short*)alloc(65536 * 2);
    short* clsBlo = (short*)alloc(65536 * 2);
    short* w1hi   = (short*)alloc(6144 * 2);
    short* w1lo   = (short*)alloc(6144 * 2);

    const int EperB = (E_ + HB - 1) / HB;
    const int nb = (N_ + 1023) / 1024;

    hipMemsetAsync(h_b + (size_t)N_ * 128, 0, 256, stream);   // zero row for pads

    hist_kernel<<<2 * HB, 1024, 0, stream>>>(src, dst, histW, E_, EperB);
    merge_kernel<<<(NN2 + 255) / 256, 256, 0, stream>>>(
        (const unsigned short*)histW, pdeg, bp16, norm_src, norm_dst, N_);
    scan_partial_kernel<<<nb, 256, 0, stream>>>(pdeg, bsums, N_);
    scan_bsums_kernel<<<1, 64, 0, stream>>>(bsums, offs, nb, N_);
    scan_final_kernel<<<nb, 256, 0, stream>>>(pdeg, bsums, offs, N_);
    fill_pad_kernel<<<(cscCap / 4 + 255) / 256, 256, 0, stream>>>(csc, cscCap, N_);
    fill_kernel<<<HB, 1024, 0, stream>>>(src, dst, offs, bp16, csc, E_, EperB);

    pack_all_kernel<<<(16384 + 768 + 255) / 256, 256, 0, stream>>>(
        enc_W, cls_W0, cls_W1, encBhi, encBlo, clsBhi, clsBlo, w1hi, w1lo);

    const int gblocks = (N_ + 127) / 128;
    const int agg_blocks = (N_ + 3) / 4;

    for (int i = 0; i < 4; ++i) {
        if (i == 0)
            mfma_gemm_kernel<false><<<gblocks, 256, 0, stream>>>(
                feat, encBhi, encBlo, norm_src, h_b, N_);
        else
            mfma_gemm_kernel<true><<<gblocks, 256, 0, stream>>>(
                hl[i - 1], encBhi + i * 16384, encBlo + i * 16384, norm_src, h_b, N_);
        aggregate_kernel<<<agg_blocks, 256, 0, stream>>>(
            h_b, offs, csc, norm_dst,
            (i == 3) ? enc_bias : nullptr,
            bn_gamma + i * 128, bn_beta + i * 128, bn_mean + i * 128, bn_var + i * 128,
            hl[i], N_);
    }
    classifier_kernel<<<gblocks, 256, 0, stream>>>(
        hl[0], hl[1], hl[2], hl[3], clsBhi, clsBlo, w1hi, w1lo, cls_b0,
        cls_g0, cls_be0, cls_m0, cls_v0, cls_b1, out, N_);
}